// Round 7
// baseline (19.995 us; speedup 1.0000x reference)
//
#include <hip/hip_runtime.h>
#include <float.h>

#define INPUT_DIM 2304
#define SUB_DIM 64
#define ATOMS 512
#define NUM_EXPERTS 256
#define TOPK 4
#define NBLK 128

// offset = 1/sqrt(2304) = 1/48 exactly
#define OFFSET (1.0f / 48.0f)
#define MAGIC 0x9E3779B9u

typedef unsigned long long u64;

// ---- payload-in-flag primitives: single 8B relaxed agent atomics (sc1, L3 coherence point) ----
__device__ __forceinline__ u64 pair_ld(const u64* p) {
    return __hip_atomic_load(p, __ATOMIC_RELAXED, __HIP_MEMORY_SCOPE_AGENT);
}
__device__ __forceinline__ void pair_st(u64* p, u64 v) {
    __hip_atomic_store(p, v, __ATOMIC_RELAXED, __HIP_MEMORY_SCOPE_AGENT);
}
__device__ __forceinline__ u64 pack(float f) {
    return ((u64)__float_as_uint(f) << 32) | (u64)MAGIC;
}
__device__ __forceinline__ bool pvalid(u64 v) { return (unsigned)v == MAGIC; }
__device__ __forceinline__ float payload(u64 v) { return __uint_as_float((unsigned)(v >> 32)); }

// ws layout (u64 units):
//   pair_code[128 readers][256 rows]   @ 0        (256 KB)
//   pair_sub [4 experts][64]           @ 32768    (2 KB)
//   pair_dec [36 readers][256]         @ 33024    (72 KB)
// MAGIC protocol; readers zero consumed pairs; poison 0xAA.. != MAGIC; no memset node.

__global__ void __launch_bounds__(256, 1) moe_fused(
    const float* __restrict__ x,
    const float* __restrict__ enc_top,
    const float* __restrict__ W_down,
    const float* __restrict__ enc_w,
    float* __restrict__ out,
    float* __restrict__ ws_f)
{
    u64* pc = (u64*)ws_f;           // [128][256]
    u64* ps = pc + 128 * 256;       // [4][64]
    u64* pd = ps + 4 * 64;          // [36][256]

    __shared__ float s_red[256];
    __shared__ float s_ec[ATOMS];
    __shared__ float s_decp[16][SUB_DIM];
    __shared__ float s_sub[SUB_DIM];
    __shared__ float s_dec[SUB_DIM];
    __shared__ int   s_idx[TOPK];
    __shared__ float s_val[TOPK];

    const int b    = blockIdx.x;    // 0..127
    const int t    = threadIdx.x;   // 0..255
    const int lane = t & 63;
    const int wave = t >> 6;
    const float4* x4 = (const float4*)x;

    // P3 blocks: preload x into registers while P1 runs elsewhere
    float4 xr[INPUT_DIM / 256];
    if (b >= 64) {
        #pragma unroll
        for (int i = 0; i < INPUT_DIM / 256; ++i) xr[i] = x4[lane + 64 * i];
    }

    // ================= P1: codes (blocks 0..63, one row per wave) =================
    if (b < 64) {
        const int row = b * 4 + wave;
        const float4* row4 = (const float4*)(enc_top + (size_t)row * INPUT_DIM);
        float acc = 0.0f;
        #pragma unroll
        for (int i = 0; i < INPUT_DIM / 256; ++i) {
            float4 w  = row4[lane + 64 * i];
            float4 xv = x4[lane + 64 * i];
            acc += w.x * xv.x + w.y * xv.y + w.z * xv.z + w.w * xv.w;
        }
        #pragma unroll
        for (int o = 32; o > 0; o >>= 1) acc += __shfl_down(acc, o);
        float c = __shfl(acc, 0);
        c = (c >= OFFSET) ? c : 0.0f;
        const u64 pv = pack(c);
        // fan-out: each lane serves 2 readers (lane, lane+64); single 8B atomic = data+flag
        pair_st(&pc[(size_t)lane * 256 + row], pv);
        pair_st(&pc[(size_t)(lane + 64) * 256 + row], pv);
    }

    if (b >= 40 && b < 64) return;      // pure P1 producers

    // ================= P2: local top-4 (wave0; poll returns codes directly) =================
    if (wave == 0) {
        u64 v0, v1, v2, v3;
        for (;;) {
            v0 = pair_ld(&pc[(size_t)b * 256 + lane]);
            v1 = pair_ld(&pc[(size_t)b * 256 + lane + 64]);
            v2 = pair_ld(&pc[(size_t)b * 256 + lane + 128]);
            v3 = pair_ld(&pc[(size_t)b * 256 + lane + 192]);
            if (__all(pvalid(v0) && pvalid(v1) && pvalid(v2) && pvalid(v3))) break;
        }
        float v[4] = { payload(v0), payload(v1), payload(v2), payload(v3) };
        int   id[4] = { lane, lane + 64, lane + 128, lane + 192 };
        for (int k = 0; k < TOPK; ++k) {
            float bv = v[0]; int bi = id[0];
            #pragma unroll
            for (int i = 1; i < 4; ++i)
                if (v[i] > bv || (v[i] == bv && id[i] < bi)) { bv = v[i]; bi = id[i]; }
            #pragma unroll
            for (int o = 32; o > 0; o >>= 1) {
                float ov = __shfl_down(bv, o);
                int   oi = __shfl_down(bi, o);
                if (ov > bv || (ov == bv && oi < bi)) { bv = ov; bi = oi; }
            }
            bv = __shfl(bv, 0);
            bi = __shfl(bi, 0);
            if (lane == 0) { s_idx[k] = bi; s_val[k] = bv; }
            #pragma unroll
            for (int i = 0; i < 4; ++i)
                if (id[i] == bi) v[i] = -FLT_MAX;
        }
        // reset consumed pairs (off critical path)
        pair_st(&pc[(size_t)b * 256 + lane], 0ull);
        pair_st(&pc[(size_t)b * 256 + lane + 64], 0ull);
        pair_st(&pc[(size_t)b * 256 + lane + 128], 0ull);
        pair_st(&pc[(size_t)b * 256 + lane + 192], 0ull);
    }
    __syncthreads();

    // ================= P3: sub rows (blocks 64..127, one row per wave) =================
    if (b >= 64) {
        const int r = (b - 64) * 4 + wave;      // 0..255
        const int E = s_idx[r >> 6];
        const float4* row4 = (const float4*)(W_down + ((size_t)E * SUB_DIM + (r & 63)) * INPUT_DIM);
        float acc = 0.0f;
        #pragma unroll
        for (int i = 0; i < INPUT_DIM / 256; ++i) {
            float4 w = row4[lane + 64 * i];
            acc += w.x * xr[i].x + w.y * xr[i].y + w.z * xr[i].z + w.w * xr[i].w;
        }
        #pragma unroll
        for (int o = 32; o > 0; o >>= 1) acc += __shfl_down(acc, o);
        if (lane == 0) pair_st(&ps[r], pack(acc));   // one 8B atomic: data+flag, no sync needed
        return;
    }

    // ================= P4: expert encode+decode (blocks 0..3) =================
    if (b < TOPK) {
        const int E = s_idx[b];
        const float* W = enc_w + (size_t)E * ATOMS * SUB_DIM;
        // prefetch into L2: one float4 per 64B line, issued before the poll
        float pf = 0.0f;
        #pragma unroll
        for (int i = 0; i < 8; ++i) {
            float4 w = ((const float4*)W)[(size_t)(t + i * 256) * 4];
            pf += w.x + w.y + w.z + w.w;
        }
        if (wave == 0) {
            u64 v;
            for (;;) {
                v = pair_ld(&ps[b * SUB_DIM + lane]);
                if (__all(pvalid(v))) break;
            }
            s_sub[lane] = payload(v);
            pair_st(&ps[b * SUB_DIM + lane], 0ull);
        }
        asm volatile("" :: "v"(pf));   // keep prefetch alive
        __syncthreads();
        // encode: 2 atoms per thread
        #pragma unroll
        for (int rr = 0; rr < ATOMS / 256; ++rr) {
            int a = t + rr * 256;
            const float4* row4 = (const float4*)(W + (size_t)a * SUB_DIM);
            float acc = 0.0f;
            #pragma unroll
            for (int i = 0; i < SUB_DIM / 4; ++i) {
                float4 w = row4[i];
                acc += w.x * s_sub[4*i] + w.y * s_sub[4*i+1] + w.z * s_sub[4*i+2] + w.w * s_sub[4*i+3];
            }
            s_ec[a] = (acc >= OFFSET) ? acc : 0.01f * acc;   // leaky slope .01
        }
        __syncthreads();
        // decode, tiled
        {
            const int sg = t & 15, ch = t >> 4;
            float4 a4 = make_float4(0.f, 0.f, 0.f, 0.f);
            for (int a = ch * 32; a < ch * 32 + 32; ++a) {
                float4 w = *(const float4*)(W + (size_t)a * SUB_DIM + sg * 4);
                float  e = s_ec[a];
                a4.x += w.x * e; a4.y += w.y * e; a4.z += w.z * e; a4.w += w.w * e;
            }
            *(float4*)&s_decp[ch][sg * 4] = a4;
        }
        __syncthreads();
        if (t < SUB_DIM) {
            float d = 0.0f;
            #pragma unroll
            for (int c = 0; c < 16; ++c) d += s_decp[c][t];
            s_dec[t] = d;
        }
        __syncthreads();
        // fan-out dec to 36 readers: thread t covers readers wave+4i, value s_dec[lane]
        {
            const u64 pv = pack(s_dec[lane]);
            #pragma unroll
            for (int i = 0; i < 9; ++i) {
                const int r = wave + 4 * i;     // 0..35
                pair_st(&pd[(size_t)r * 256 + b * SUB_DIM + lane], pv);
            }
        }
        return;
    }

    // ================= P5: recon (blocks 4..39); W preloaded during P3/P4 window =================
    {
        const int rb = b - 4;                  // 0..35
        const int d  = rb * 64 + lane;
        const int E  = s_idx[wave];            // one expert per wave
        float wr[SUB_DIM];
        const float* Wb = W_down + (size_t)E * SUB_DIM * INPUT_DIM + d;
        #pragma unroll
        for (int s = 0; s < SUB_DIM; ++s) wr[s] = Wb[(size_t)s * INPUT_DIM];
        const float et = s_val[wave] * enc_top[(size_t)E * INPUT_DIM + d];
        // each wave polls ITS OWN expert's 64 dec pairs — payload arrives with the flag
        u64 v;
        for (;;) {
            v = pair_ld(&pd[(size_t)rb * 256 + wave * SUB_DIM + lane]);
            if (__all(pvalid(v))) break;
        }
        float dv = payload(v);
        pair_st(&pd[(size_t)rb * 256 + wave * SUB_DIM + lane], 0ull);
        float acc = et;
        #pragma unroll
        for (int s = 0; s < SUB_DIM; ++s)
            acc += wr[s] * __shfl(dv, s);
        s_red[t] = acc;
        __syncthreads();
        if (t < 64)
            out[rb * 64 + t] = s_red[t] + s_red[t + 64] + s_red[t + 128] + s_red[t + 192];
    }
}

extern "C" void kernel_launch(void* const* d_in, const int* in_sizes, int n_in,
                              void* d_out, int out_size, void* d_ws, size_t ws_size,
                              hipStream_t stream) {
    const float* x       = (const float*)d_in[0];
    const float* enc_top = (const float*)d_in[1];
    const float* W_down  = (const float*)d_in[2];
    const float* enc_w   = (const float*)d_in[3];
    float* out = (float*)d_out;
    float* ws  = (float*)d_ws;

    moe_fused<<<dim3(NBLK), dim3(256), 0, stream>>>(x, enc_top, W_down, enc_w, out, ws);
}

// Round 8
// 17.329 us; speedup vs baseline: 1.1539x; 1.1539x over previous
//
#include <hip/hip_runtime.h>
#include <float.h>

#define INPUT_DIM 2304
#define SUB_DIM 64
#define ATOMS 512
#define NUM_EXPERTS 256
#define TOPK 4

// offset = 1/sqrt(2304) = 1/48 exactly
#define OFFSET (1.0f / 48.0f)
#define MAGIC 0x9E3779B9u

typedef unsigned long long u64;

// ---- payload-in-flag: single 8B relaxed agent atomics (sc1, L3 coherence point) ----
__device__ __forceinline__ u64 pair_ld(const u64* p) {
    return __hip_atomic_load(p, __ATOMIC_RELAXED, __HIP_MEMORY_SCOPE_AGENT);
}
__device__ __forceinline__ void pair_st(u64* p, u64 v) {
    __hip_atomic_store(p, v, __ATOMIC_RELAXED, __HIP_MEMORY_SCOPE_AGENT);
}
__device__ __forceinline__ u64 pack(float f) {
    return ((u64)__float_as_uint(f) << 32) | (u64)MAGIC;
}
__device__ __forceinline__ bool pvalid(u64 v) { return (unsigned)v == MAGIC; }
__device__ __forceinline__ float payload(u64 v) { return __uint_as_float((unsigned)(v >> 32)); }
__device__ __forceinline__ float dot4(float4 a, float4 b) {
    return a.x * b.x + a.y * b.y + a.z * b.z + a.w * b.w;
}

// ws layout (u64 units):
//   pc[256 readers][256 rows]                @ 0       (512 KB)
//   ps[2 half-copies][256 rows]              @ 65536   (4 KB)
//   pd[36 readers][4 experts][2 halves][64]  @ 66048   (144 KB)
// MAGIC protocol; every slot has exactly ONE consumer which resets it to 0
// (poison 0xAA.. != MAGIC, so first call works; resets keep replays honest).

__global__ void __launch_bounds__(256, 1) moe_fused(
    const float* __restrict__ x,
    const float* __restrict__ enc_top,
    const float* __restrict__ W_down,
    const float* __restrict__ enc_w,
    float* __restrict__ out,
    float* __restrict__ ws_f)
{
    u64* pc = (u64*)ws_f;           // [256][256]
    u64* ps = pc + 256 * 256;       // [2][256]
    u64* pd = ps + 2 * 256;         // [36][4][2][64]

    __shared__ float s_red[256];
    __shared__ float s_bc;
    __shared__ float s_sub[SUB_DIM];
    __shared__ float s_ec[256];               // per-half atoms
    __shared__ float s_decp[16][SUB_DIM];
    __shared__ float s_dec[SUB_DIM];
    __shared__ int   s_idx[TOPK];
    __shared__ float s_val[TOPK];

    const int b    = blockIdx.x;    // 0..255
    const int t    = threadIdx.x;   // 0..255
    const int lane = t & 63;
    const int wave = t >> 6;
    const float4* x4 = (const float4*)x;

    // ================= P1: code row b (256-thread dot, 3 loads deep) =================
    {
        const float4* row4 = (const float4*)(enc_top + (size_t)b * INPUT_DIM);
        float acc = dot4(row4[t], x4[t]) + dot4(row4[t + 256], x4[t + 256]);
        if (t < 64) acc += dot4(row4[t + 512], x4[t + 512]);
        #pragma unroll
        for (int o = 32; o > 0; o >>= 1) acc += __shfl_down(acc, o);
        if (lane == 0) s_red[wave] = acc;
        __syncthreads();
        if (t == 0) {
            float s = s_red[0] + s_red[1] + s_red[2] + s_red[3];
            s_bc = (s >= OFFSET) ? s : 0.0f;
        }
        __syncthreads();
        // fan-out: one 8B store per thread -> reader t
        pair_st(&pc[(size_t)t * 256 + b], pack(s_bc));
    }

    // ================= P2: wave0 polls all 256 codes, local top-4 =================
    if (wave == 0) {
        u64 v0, v1, v2, v3;
        for (;;) {
            v0 = pair_ld(&pc[(size_t)b * 256 + lane]);
            v1 = pair_ld(&pc[(size_t)b * 256 + lane + 64]);
            v2 = pair_ld(&pc[(size_t)b * 256 + lane + 128]);
            v3 = pair_ld(&pc[(size_t)b * 256 + lane + 192]);
            if (__all(pvalid(v0) && pvalid(v1) && pvalid(v2) && pvalid(v3))) break;
        }
        float v[4] = { payload(v0), payload(v1), payload(v2), payload(v3) };
        int   id[4] = { lane, lane + 64, lane + 128, lane + 192 };
        for (int k = 0; k < TOPK; ++k) {
            float bv = v[0]; int bi = id[0];
            #pragma unroll
            for (int i = 1; i < 4; ++i)
                if (v[i] > bv || (v[i] == bv && id[i] < bi)) { bv = v[i]; bi = id[i]; }
            #pragma unroll
            for (int o = 32; o > 0; o >>= 1) {
                float ov = __shfl_down(bv, o);
                int   oi = __shfl_down(bi, o);
                if (ov > bv || (ov == bv && oi < bi)) { bv = ov; bi = oi; }
            }
            bv = __shfl(bv, 0);
            bi = __shfl(bi, 0);
            if (lane == 0) { s_idx[k] = bi; s_val[k] = bv; }
            #pragma unroll
            for (int i = 0; i < 4; ++i)
                if (id[i] == bi) v[i] = -FLT_MAX;
        }
        // reset consumed pairs
        pair_st(&pc[(size_t)b * 256 + lane], 0ull);
        pair_st(&pc[(size_t)b * 256 + lane + 64], 0ull);
        pair_st(&pc[(size_t)b * 256 + lane + 128], 0ull);
        pair_st(&pc[(size_t)b * 256 + lane + 192], 0ull);
    }
    __syncthreads();

    // ================= P4 prefetch issue (blocks 0..7), fire-and-forget =================
    const float* Wexp = nullptr;
    float pf = 0.0f;
    if (b < 8) {
        const int e = b >> 1, h = b & 1;
        Wexp = enc_w + (size_t)s_idx[e] * ATOMS * SUB_DIM + (size_t)h * 256 * SUB_DIM;
        // touch one float4 per 64B line: 1024 lines / 256 threads = 4 each
        #pragma unroll
        for (int i = 0; i < 4; ++i) {
            float4 w = ((const float4*)Wexp)[(size_t)(t + i * 256) * 4];
            pf += w.x + w.y + w.z + w.w;
        }
    }

    // ================= P3: sub row b (256-thread dot) =================
    {
        const int E = s_idx[b >> 6];
        const float4* row4 = (const float4*)(W_down + ((size_t)E * SUB_DIM + (b & 63)) * INPUT_DIM);
        float acc = dot4(row4[t], x4[t]) + dot4(row4[t + 256], x4[t + 256]);
        if (t < 64) acc += dot4(row4[t + 512], x4[t + 512]);
        #pragma unroll
        for (int o = 32; o > 0; o >>= 1) acc += __shfl_down(acc, o);
        if (lane == 0) s_red[wave] = acc;
        __syncthreads();
        if (t == 0) {
            float s = s_red[0] + s_red[1] + s_red[2] + s_red[3];
            const u64 pv = pack(s);
            pair_st(&ps[b], pv);          // copy for half 0
            pair_st(&ps[256 + b], pv);    // copy for half 1
        }
    }

    if (b >= 44) return;

    // ================= P4: expert encode+decode, 2 blocks per expert =================
    if (b < 8) {
        const int e = b >> 1, h = b & 1;
        if (wave == 0) {
            u64 v;
            for (;;) {
                v = pair_ld(&ps[h * 256 + e * SUB_DIM + lane]);
                if (__all(pvalid(v))) break;
            }
            s_sub[lane] = payload(v);
            pair_st(&ps[h * 256 + e * SUB_DIM + lane], 0ull);
        }
        asm volatile("" :: "v"(pf));   // keep prefetch alive
        __syncthreads();
        // encode: 1 atom per thread (within-half atom t)
        {
            const float4* row4 = (const float4*)(Wexp + (size_t)t * SUB_DIM);
            float acc = 0.0f;
            #pragma unroll
            for (int i = 0; i < SUB_DIM / 4; ++i) {
                float4 w = row4[i];
                acc += w.x * s_sub[4*i] + w.y * s_sub[4*i+1] + w.z * s_sub[4*i+2] + w.w * s_sub[4*i+3];
            }
            s_ec[t] = (acc >= OFFSET) ? acc : 0.01f * acc;   // leaky slope .01
        }
        __syncthreads();
        // decode (partial over this half's 256 atoms), tiled 16 atoms x 4 s-cols
        {
            const int sg = t & 15, ch = t >> 4;
            float4 a4 = make_float4(0.f, 0.f, 0.f, 0.f);
            for (int aa = ch * 16; aa < ch * 16 + 16; ++aa) {
                float4 w = *(const float4*)(Wexp + (size_t)aa * SUB_DIM + sg * 4);
                float  ec = s_ec[aa];
                a4.x += w.x * ec; a4.y += w.y * ec; a4.z += w.z * ec; a4.w += w.w * ec;
            }
            *(float4*)&s_decp[ch][sg * 4] = a4;
        }
        __syncthreads();
        if (t < SUB_DIM) {
            float d = 0.0f;
            #pragma unroll
            for (int c = 0; c < 16; ++c) d += s_decp[c][t];
            s_dec[t] = d;
        }
        __syncthreads();
        // fan-out partial dec to 36 readers
        {
            const u64 pv = pack(s_dec[lane]);
            #pragma unroll
            for (int i = 0; i < 9; ++i) {
                const int r = wave + 4 * i;   // 0..35
                pair_st(&pd[(((size_t)r * TOPK + e) * 2 + h) * 64 + lane], pv);
            }
        }
        return;
    }

    // ================= P5: recon (blocks 8..43); preload during P4 window =================
    {
        const int rb = b - 8;                  // 0..35
        const int d  = rb * 64 + lane;
        const int E  = s_idx[wave];            // one expert per wave
        float wr[SUB_DIM];
        const float* Wb = W_down + (size_t)E * SUB_DIM * INPUT_DIM + d;
        #pragma unroll
        for (int s = 0; s < SUB_DIM; ++s) wr[s] = Wb[(size_t)s * INPUT_DIM];
        const float et = s_val[wave] * enc_top[(size_t)E * INPUT_DIM + d];
        // poll both half-dec partials for this wave's expert
        u64 v0, v1;
        for (;;) {
            v0 = pair_ld(&pd[(((size_t)rb * TOPK + wave) * 2 + 0) * 64 + lane]);
            v1 = pair_ld(&pd[(((size_t)rb * TOPK + wave) * 2 + 1) * 64 + lane]);
            if (__all(pvalid(v0) && pvalid(v1))) break;
        }
        float dv = payload(v0) + payload(v1);
        pair_st(&pd[(((size_t)rb * TOPK + wave) * 2 + 0) * 64 + lane], 0ull);
        pair_st(&pd[(((size_t)rb * TOPK + wave) * 2 + 1) * 64 + lane], 0ull);
        float acc = et;
        #pragma unroll
        for (int s = 0; s < SUB_DIM; ++s)
            acc += wr[s] * __shfl(dv, s);
        s_red[t] = acc;
        __syncthreads();
        if (t < 64)
            out[rb * 64 + t] = s_red[t] + s_red[t + 64] + s_red[t + 128] + s_red[t + 192];
    }
}

extern "C" void kernel_launch(void* const* d_in, const int* in_sizes, int n_in,
                              void* d_out, int out_size, void* d_ws, size_t ws_size,
                              hipStream_t stream) {
    const float* x       = (const float*)d_in[0];
    const float* enc_top = (const float*)d_in[1];
    const float* W_down  = (const float*)d_in[2];
    const float* enc_w   = (const float*)d_in[3];
    float* out = (float*)d_out;
    float* ws  = (float*)d_ws;

    moe_fused<<<dim3(256), dim3(256), 0, stream>>>(x, enc_top, W_down, enc_w, out, ws);
}